// Round 5
// baseline (1496.481 us; speedup 1.0000x reference)
//
#include <hip/hip_runtime.h>

// dims
#define BB 2
#define TT 2048
#define HID 2048
#define HK 16
#define HV 32
#define DK 128
#define DV 128
#define KW 4
#define KEY_DIM 2048
#define VAL_DIM 4096
#define CONV_DIM 8192
#define N1PAD 12416     // 12352 padded to 128
#define M_ROWS 4096     // B*T
#define CHUNK 32        // scan chunk (timesteps staged per barrier)

typedef __attribute__((ext_vector_type(8))) short short8;
typedef __attribute__((ext_vector_type(8))) unsigned short ushort8;
typedef __attribute__((ext_vector_type(4))) float f32x4;

__device__ __forceinline__ unsigned short f2bf(float f) {
  union { float f; unsigned int u; } v; v.f = f;
  unsigned int r = v.u + 0x7FFFu + ((v.u >> 16) & 1u);
  return (unsigned short)(r >> 16);
}
__device__ __forceinline__ float bf2f(unsigned short u) {
  union { unsigned int u; float f; } v; v.u = ((unsigned int)u) << 16; return v.f;
}
__device__ __forceinline__ float bitsf(unsigned int u) {
  union { unsigned int u; float f; } v; v.u = u; return v.f;
}

__device__ __forceinline__ void gload_lds16(const unsigned short* g, unsigned short* l) {
  __builtin_amdgcn_global_load_lds((const __attribute__((address_space(1))) unsigned int*)g,
                                   (__attribute__((address_space(3))) unsigned int*)l,
                                   16, 0, 0);
}
__device__ __forceinline__ void gload_lds4(const float* g, unsigned short* l) {
  __builtin_amdgcn_global_load_lds((const __attribute__((address_space(1))) unsigned int*)g,
                                   (__attribute__((address_space(3))) unsigned int*)l,
                                   4, 0, 0);
}

// ---------------- conversions ----------------
__global__ void cvt_bf16(const float* __restrict__ in, unsigned short* __restrict__ out) {
  long i = ((long)blockIdx.x * 256 + threadIdx.x) * 4;
  float4 v = *(const float4*)&in[i];
  unsigned long long p = (unsigned long long)f2bf(v.x)
                       | ((unsigned long long)f2bf(v.y) << 16)
                       | ((unsigned long long)f2bf(v.z) << 32)
                       | ((unsigned long long)f2bf(v.w) << 48);
  *(unsigned long long*)&out[i] = p;
}

__global__ void build_wcat(const float* __restrict__ wqkv, const float* __restrict__ wz,
                           const float* __restrict__ wb, const float* __restrict__ wa,
                           unsigned short* __restrict__ wcat) {
  long idx = (long)blockIdx.x * 256 + threadIdx.x;
  long e = idx * 4;
  long r = e >> 11;
  int cc = (int)(e & 2047);
  unsigned long long p = 0ULL;
  if (r < 12352) {
    const float* src;
    if (r < 8192)       src = wqkv + r * 2048;
    else if (r < 12288) src = wz + (r - 8192) * 2048;
    else if (r < 12320) src = wb + (r - 12288) * 2048;
    else                src = wa + (r - 12320) * 2048;
    float4 v = *(const float4*)&src[cc];
    p = (unsigned long long)f2bf(v.x)
      | ((unsigned long long)f2bf(v.y) << 16)
      | ((unsigned long long)f2bf(v.z) << 32)
      | ((unsigned long long)f2bf(v.w) << 48);
  }
  *(unsigned long long*)&wcat[e] = p;
}

// ---------------- GEMM: C[M,N] = A[M,K] * W[N,K]^T ----------------
template <bool BF16OUT>
__global__ __launch_bounds__(256) void gemm_bt(const unsigned short* __restrict__ A,
                                               const unsigned short* __restrict__ Bw,
                                               void* __restrict__ Cout,
                                               int N, int K) {
  __shared__ unsigned short lds[8192];
  const int tid = threadIdx.x;
  const int wid = tid >> 6;
  const int lane = tid & 63;
  const int m0 = blockIdx.y << 7;
  const int n0 = blockIdx.x << 7;
  const int wr = wid >> 1, wc = wid & 1;

  f32x4 acc[4][4] = {};

  const int srow = (wid << 4) + (lane >> 2);
  const int scol = (lane & 3) << 3;
  const unsigned short* gA0 = A + (long)(m0 + srow) * K + scol;
  const unsigned short* gA1 = A + (long)(m0 + 64 + srow) * K + scol;
  const unsigned short* gB0 = Bw + (long)(n0 + srow) * K + scol;
  const unsigned short* gB1 = Bw + (long)(n0 + 64 + srow) * K + scol;
  unsigned short* ldsA = &lds[wid << 9];
  unsigned short* ldsB = &lds[4096 + (wid << 9)];

  const int lrow = lane & 15;
  const int lk = (lane >> 4) << 3;

  for (int k0 = 0; k0 < K; k0 += 32) {
    __syncthreads();
    gload_lds16(gA0 + k0, ldsA);
    gload_lds16(gA1 + k0, ldsA + 2048);
    gload_lds16(gB0 + k0, ldsB);
    gload_lds16(gB1 + k0, ldsB + 2048);
    __syncthreads();
    short8 av[4], bv[4];
#pragma unroll
    for (int i = 0; i < 4; ++i) {
      av[i] = *(const short8*)&lds[((wr << 6) + (i << 4) + lrow) * 32 + lk];
      bv[i] = *(const short8*)&lds[4096 + ((wc << 6) + (i << 4) + lrow) * 32 + lk];
    }
#pragma unroll
    for (int i = 0; i < 4; ++i)
#pragma unroll
      for (int j = 0; j < 4; ++j)
        acc[i][j] = __builtin_amdgcn_mfma_f32_16x16x32_bf16(av[i], bv[j], acc[i][j], 0, 0, 0);
  }
  const int rbase = m0 + (wr << 6) + ((lane >> 4) << 2);
  const int cbase = n0 + (wc << 6) + (lane & 15);
#pragma unroll
  for (int i = 0; i < 4; ++i)
#pragma unroll
    for (int j = 0; j < 4; ++j)
#pragma unroll
      for (int r = 0; r < 4; ++r) {
        long idx = (long)(rbase + (i << 4) + r) * N + cbase + (j << 4);
        if (BF16OUT) ((unsigned short*)Cout)[idx] = f2bf(acc[i][j][r]);
        else         ((float*)Cout)[idx] = acc[i][j][r];
      }
}

// ---------------- depthwise causal conv1d + silu (8 channels/thread) ----------------
__global__ __launch_bounds__(256) void conv_silu(const unsigned short* __restrict__ C1,
                                                 const float* __restrict__ convw,
                                                 unsigned short* __restrict__ qb,
                                                 unsigned short* __restrict__ kb,
                                                 unsigned short* __restrict__ vb) {
  const int bid = blockIdx.x;             // 512 = cb(4) * tblk(64) * b(2)
  const int cb = bid & 3, tblk = (bid >> 2) & 63, b = bid >> 8;
  const int c0 = cb * 2048 + threadIdx.x * 8;
  float w0[8], w1[8], w2[8], w3[8];
#pragma unroll
  for (int j = 0; j < 8; ++j) {
    float4 wv = *(const float4*)&convw[(c0 + j) * 4];
    w0[j] = wv.x; w1[j] = wv.y; w2[j] = wv.z; w3[j] = wv.w;
  }
  const int t0 = tblk * 32;
  const long rowbase = ((long)b * TT) * N1PAD + c0;
  float x0[8], x1[8], x2[8];
#pragma unroll
  for (int j = 0; j < 8; ++j) { x0[j] = 0.f; x1[j] = 0.f; x2[j] = 0.f; }
  if (t0 >= 1) { ushort8 r = *(const ushort8*)&C1[rowbase + (long)(t0 - 1) * N1PAD];
#pragma unroll
    for (int j = 0; j < 8; ++j) x2[j] = bf2f(r[j]); }
  if (t0 >= 2) { ushort8 r = *(const ushort8*)&C1[rowbase + (long)(t0 - 2) * N1PAD];
#pragma unroll
    for (int j = 0; j < 8; ++j) x1[j] = bf2f(r[j]); }
  if (t0 >= 3) { ushort8 r = *(const ushort8*)&C1[rowbase + (long)(t0 - 3) * N1PAD];
#pragma unroll
    for (int j = 0; j < 8; ++j) x0[j] = bf2f(r[j]); }

  for (int t = t0; t < t0 + 32; ++t) {
    ushort8 rr = *(const ushort8*)&C1[rowbase + (long)t * N1PAD];
    ushort8 outp;
#pragma unroll
    for (int j = 0; j < 8; ++j) {
      float x3 = bf2f(rr[j]);
      float y = w0[j] * x0[j] + w1[j] * x1[j] + w2[j] * x2[j] + w3[j] * x3;
      y = y / (1.f + __expf(-y));
      outp[j] = f2bf(y);
      x0[j] = x1[j]; x1[j] = x2[j]; x2[j] = x3;
    }
    long m = (long)b * TT + t;
    if (cb == 0)      *(ushort8*)&qb[m * 2048 + threadIdx.x * 8] = outp;
    else if (cb == 1) *(ushort8*)&kb[m * 2048 + threadIdx.x * 8] = outp;
    else              *(ushort8*)&vb[m * 4096 + (cb - 2) * 2048 + threadIdx.x * 8] = outp;
  }
}

// ---------------- g (decay) and beta ----------------
__global__ void gbeta(const unsigned short* __restrict__ C1, const float* __restrict__ Alog,
                      const float* __restrict__ dtb, float* __restrict__ egb, float* __restrict__ betab) {
  int idx = blockIdx.x * 256 + threadIdx.x;   // < 131072
  int m = idx >> 5, h = idx & 31;
  float a = bf2f(C1[(long)m * N1PAD + 12320 + h]);
  float bl = bf2f(C1[(long)m * N1PAD + 12288 + h]);
  float xsp = a + dtb[h];
  float sp = (xsp > 20.f) ? xsp : log1pf(expf(xsp));
  egb[idx] = expf(-expf(Alog[h]) * sp);
  betab[idx] = 1.f / (1.f + expf(-bl));
}

// ---------------- l2 norm over DK=128 (one wave per head) ----------------
__global__ __launch_bounds__(256) void l2norm(unsigned short* __restrict__ buf, float scale) {
  int hid = blockIdx.x * 4 + (threadIdx.x >> 6);
  int lane = threadIdx.x & 63;
  long off = (long)hid * 128 + lane * 2;
  unsigned int u = *(unsigned int*)&buf[off];
  float a = bf2f((unsigned short)(u & 0xffff));
  float c = bf2f((unsigned short)(u >> 16));
  float ss = a * a + c * c;
#pragma unroll
  for (int mm = 1; mm < 64; mm <<= 1) ss += __shfl_xor(ss, mm);
  float sc = scale / fmaxf(sqrtf(ss), 1e-12f);
  unsigned int pk = (unsigned int)f2bf(a * sc) | ((unsigned int)f2bf(c * sc) << 16);
  *(unsigned int*)&buf[off] = pk;
}

// ---------------- gated delta rule scan (16 lanes/col x 8 S-regs, 2 blocks/CU) ----------------
// LDS per buffer (8832 ush = 17664 B):
//   k  [CHUNK][128] @ 0        (8192 B = 2 rounds x 4 waves x 1024 B)
//   q  [CHUNK][128] @ 4096 ush
//   v  [CHUNK][16]  @ 8192 ush (1024 B = wave 2)
//   g,b f32 [32+32] @ 8704 ush (256 B = wave 3)
__global__ __launch_bounds__(256) void scan_kernel(const unsigned short* __restrict__ qb,
                                                   const unsigned short* __restrict__ kb,
                                                   const unsigned short* __restrict__ vb,
                                                   const float* __restrict__ egb,
                                                   const float* __restrict__ betab,
                                                   unsigned short* __restrict__ ob) {
  const int bi = blockIdx.x;   // 512 = vc(8) * h(32) * b(2)
  const int vc = bi & 7, h = (bi >> 3) & 31, b = bi >> 8;
  const int hk = h >> 1;
  const int tid = threadIdx.x;
  const int wid = tid >> 6, lane = tid & 63;
  const int col = tid >> 4, ks = tid & 15;   // 16 cols/block, 16 lanes/col

  __shared__ unsigned short sl[2][8832];

  float S[8];
#pragma unroll
  for (int i = 0; i < 8; ++i) S[i] = 0.f;

  const long kqoff = ((long)b * TT) * 2048 + hk * 128;
  const long voff  = ((long)b * TT) * 4096 + h * 128 + vc * 16;
  const long goff  = ((long)b * TT) * 32 + h;

  // global_load_lds writes lane l's payload at lds_base + l*size (linear);
  // per-lane global addresses must follow the same linear order.
  auto stage = [&](int bf, int t0) {
    unsigned short* base = sl[bf];
#pragma unroll
    for (int r = 0; r < 2; ++r) {
      int i = r * 256 + tid;                 // dest byte = i*16 within region
      int step = i >> 4, frag = i & 15;
      gload_lds16(kb + kqoff + (long)(t0 + step) * 2048 + frag * 8,
                  base + (r * 4 + wid) * 512);
      gload_lds16(qb + kqoff + (long)(t0 + step) * 2048 + frag * 8,
                  base + 4096 + (r * 4 + wid) * 512);
    }
    if (wid == 2) {
      // v: 1024 B; dest byte = lane*16 = (lane>>1)*32 + (lane&1)*16
      int step = lane >> 1, frag = lane & 1;
      gload_lds16(vb + voff + (long)(t0 + step) * 4096 + frag * 8,
                  base + 8192);
    } else if (wid == 3) {
      // g,b: 256 B; dest byte = lane*4
      const float* gp = (lane < 32) ? (egb + goff + (long)(t0 + lane) * 32)
                                    : (betab + goff + (long)(t0 + lane - 32) * 32);
      gload_lds4(gp, base + 8704);
    }
  };

  stage(0, 0);
  __syncthreads();

  const int kqo = ks * 8;         // ushort offset of this thread's fragment within a row
  int bf = 0;
  for (int c = 0; c < TT / CHUNK; ++c) {
    if (c + 1 < TT / CHUNK) stage(bf ^ 1, (c + 1) * CHUNK);
    const unsigned short* base = sl[bf];
    const float* gf = (const float*)(base + 8704);
    long obase = ((long)(b * TT + c * CHUNK) * 32 + h) * 128 + vc * 16 + col;
#pragma unroll 4
    for (int s = 0; s < CHUNK; ++s) {
      uint4 ka = *(const uint4*)(base + s * 128 + kqo);
      uint4 qa = *(const uint4*)(base + 4096 + s * 128 + kqo);
      float eg = gf[s];
      float bt = gf[32 + s];
      float vv = bf2f(base[8192 + s * 16 + col]);
      float kf[8], qf[8];
#define UNP(u4, f)                                                      \
      f[0]=bitsf((u4).x<<16); f[1]=bitsf((u4).x&0xffff0000u);           \
      f[2]=bitsf((u4).y<<16); f[3]=bitsf((u4).y&0xffff0000u);           \
      f[4]=bitsf((u4).z<<16); f[5]=bitsf((u4).z&0xffff0000u);           \
      f[6]=bitsf((u4).w<<16); f[7]=bitsf((u4).w&0xffff0000u);
      UNP(ka, kf) UNP(qa, qf)
#undef UNP
      // decay
#pragma unroll
      for (int i = 0; i < 8; ++i) S[i] *= eg;
      // kv = dot(k, S) over 128 (8 local + 16-lane reduce), 4-way split chains
      float kv0 = kf[0] * S[0], kv1 = kf[1] * S[1], kv2 = kf[2] * S[2], kv3 = kf[3] * S[3];
      kv0 = fmaf(kf[4], S[4], kv0);
      kv1 = fmaf(kf[5], S[5], kv1);
      kv2 = fmaf(kf[6], S[6], kv2);
      kv3 = fmaf(kf[7], S[7], kv3);
      float kv = (kv0 + kv1) + (kv2 + kv3);
      kv += __shfl_xor(kv, 1); kv += __shfl_xor(kv, 2);
      kv += __shfl_xor(kv, 4); kv += __shfl_xor(kv, 8);
      float bv = bt * (vv - kv);
      // S += k * bv;  o = dot(q, S)
      float o0, o1, o2, o3;
      S[0] = fmaf(kf[0], bv, S[0]); o0 = qf[0] * S[0];
      S[1] = fmaf(kf[1], bv, S[1]); o1 = qf[1] * S[1];
      S[2] = fmaf(kf[2], bv, S[2]); o2 = qf[2] * S[2];
      S[3] = fmaf(kf[3], bv, S[3]); o3 = qf[3] * S[3];
      S[4] = fmaf(kf[4], bv, S[4]); o0 = fmaf(qf[4], S[4], o0);
      S[5] = fmaf(kf[5], bv, S[5]); o1 = fmaf(qf[5], S[5], o1);
      S[6] = fmaf(kf[6], bv, S[6]); o2 = fmaf(qf[6], S[6], o2);
      S[7] = fmaf(kf[7], bv, S[7]); o3 = fmaf(qf[7], S[7], o3);
      float o = (o0 + o1) + (o2 + o3);
      o += __shfl_xor(o, 1); o += __shfl_xor(o, 2);
      o += __shfl_xor(o, 4); o += __shfl_xor(o, 8);
      if (ks == 0) ob[obase + (long)s * 4096] = f2bf(o);
    }
    __syncthreads();
    bf ^= 1;
  }
}

// ---------------- gated RMSNorm * silu(z) -> bf16 ----------------
__global__ __launch_bounds__(256) void norm_silu(const unsigned short* __restrict__ ob,
                                                 const unsigned short* __restrict__ C1,
                                                 const float* __restrict__ nw,
                                                 unsigned short* __restrict__ nrm) {
  int unit = blockIdx.x * 4 + (threadIdx.x >> 6);   // m*32+h
  int lane = threadIdx.x & 63;
  int m = unit >> 5, h = unit & 31;
  unsigned int uo = *(const unsigned int*)&ob[(long)unit * 128 + lane * 2];
  float o0 = bf2f((unsigned short)(uo & 0xffff));
  float o1 = bf2f((unsigned short)(uo >> 16));
  float ss = o0 * o0 + o1 * o1;
#pragma unroll
  for (int mm = 1; mm < 64; mm <<= 1) ss += __shfl_xor(ss, mm);
  float rs = rsqrtf(ss * (1.0f / 128.0f) + 1e-6f);
  unsigned int uz = *(const unsigned int*)&C1[(long)m * N1PAD + 8192 + h * 128 + lane * 2];
  float z0 = bf2f((unsigned short)(uz & 0xffff));
  float z1 = bf2f((unsigned short)(uz >> 16));
  float s0 = z0 / (1.f + expf(-z0));
  float s1 = z1 / (1.f + expf(-z1));
  float r0 = o0 * rs * nw[lane * 2] * s0;
  float r1 = o1 * rs * nw[lane * 2 + 1] * s1;
  unsigned int pk = (unsigned int)f2bf(r0) | ((unsigned int)f2bf(r1) << 16);
  *(unsigned int*)&nrm[(long)unit * 128 + lane * 2] = pk;
}

extern "C" void kernel_launch(void* const* d_in, const int* in_sizes, int n_in,
                              void* d_out, int out_size, void* d_ws, size_t ws_size,
                              hipStream_t stream) {
  const float* x    = (const float*)d_in[0];
  const float* Wqkv = (const float*)d_in[2];
  const float* Wz   = (const float*)d_in[3];
  const float* Wb   = (const float*)d_in[4];
  const float* Wa   = (const float*)d_in[5];
  const float* convw= (const float*)d_in[6];
  const float* dtb  = (const float*)d_in[7];
  const float* Alog = (const float*)d_in[8];
  const float* nw   = (const float*)d_in[9];
  const float* Wout = (const float*)d_in[10];
  float* out = (float*)d_out;

  char* ws = (char*)d_ws;
  const size_t OFF_C1    = 0;                    // bf16 [4096][12416]
  const size_t OFF_XB    = 101711872;            // bf16 [4096][2048]
  const size_t OFF_WCAT  = 118489088;            // bf16 [12416][2048]
  const size_t OFF_QB    = OFF_XB;               // over xb (post-GEMM1)
  const size_t OFF_KB    = 118489088;            // over wcat
  const size_t OFF_VB    = 135266304;            // over wcat
  const size_t OFF_EG    = 169345024;            // f32  [4096][32]
  const size_t OFF_BE    = 169869312;
  const size_t OFF_OB    = 170393600;            // bf16 [4096][32][128]
  const size_t OFF_NRM   = OFF_QB;               // over qb+kb (post-scan)
  const size_t OFF_WOUTB = OFF_VB;               // over vb (post-scan)

  unsigned short* C1    = (unsigned short*)(ws + OFF_C1);
  unsigned short* xb    = (unsigned short*)(ws + OFF_XB);
  unsigned short* wcat  = (unsigned short*)(ws + OFF_WCAT);
  unsigned short* qb    = (unsigned short*)(ws + OFF_QB);
  unsigned short* kb    = (unsigned short*)(ws + OFF_KB);
  unsigned short* vb    = (unsigned short*)(ws + OFF_VB);
  float*          egb   = (float*)(ws + OFF_EG);
  float*          betab = (float*)(ws + OFF_BE);
  unsigned short* ob    = (unsigned short*)(ws + OFF_OB);
  unsigned short* nrm   = (unsigned short*)(ws + OFF_NRM);
  unsigned short* woutb = (unsigned short*)(ws + OFF_WOUTB);
  (void)ws_size; (void)in_sizes; (void)n_in; (void)out_size;

  cvt_bf16<<<8192, 256, 0, stream>>>(x, xb);
  build_wcat<<<24832, 256, 0, stream>>>(Wqkv, Wz, Wb, Wa, wcat);
  gemm_bt<true><<<dim3(N1PAD / 128, M_ROWS / 128), 256, 0, stream>>>(xb, wcat, C1, N1PAD, 2048);
  conv_silu<<<512, 256, 0, stream>>>(C1, convw, qb, kb, vb);
  gbeta<<<512, 256, 0, stream>>>(C1, Alog, dtb, egb, betab);
  l2norm<<<16384, 256, 0, stream>>>(qb, 0.08838834764831845f);   // fold DK^-0.5 into q
  l2norm<<<16384, 256, 0, stream>>>(kb, 1.0f);
  scan_kernel<<<512, 256, 0, stream>>>(qb, kb, vb, egb, betab, ob);
  cvt_bf16<<<8192, 256, 0, stream>>>(Wout, woutb);
  norm_silu<<<32768, 256, 0, stream>>>(ob, C1, nw, nrm);
  gemm_bt<false><<<dim3(2048 / 128, M_ROWS / 128), 256, 0, stream>>>(nrm, woutb, out, 2048, 4096);
}

// Round 6
// 1172.029 us; speedup vs baseline: 1.2768x; 1.2768x over previous
//
#include <hip/hip_runtime.h>

// dims
#define BB 2
#define TT 2048
#define HID 2048
#define HK 16
#define HV 32
#define DK 128
#define DV 128
#define KW 4
#define KEY_DIM 2048
#define VAL_DIM 4096
#define CONV_DIM 8192
#define N1PAD 12416     // 12352 padded to 128
#define M_ROWS 4096     // B*T
#define CHUNK 32        // scan chunk (timesteps staged per barrier)

typedef __attribute__((ext_vector_type(8))) short short8;
typedef __attribute__((ext_vector_type(8))) unsigned short ushort8;
typedef __attribute__((ext_vector_type(4))) float f32x4;

__device__ __forceinline__ unsigned short f2bf(float f) {
  union { float f; unsigned int u; } v; v.f = f;
  unsigned int r = v.u + 0x7FFFu + ((v.u >> 16) & 1u);
  return (unsigned short)(r >> 16);
}
__device__ __forceinline__ float bf2f(unsigned short u) {
  union { unsigned int u; float f; } v; v.u = ((unsigned int)u) << 16; return v.f;
}
__device__ __forceinline__ float bitsf(unsigned int u) {
  union { unsigned int u; float f; } v; v.u = u; return v.f;
}

// pure-VALU cross-lane add via DPP (no LDS traffic, unlike __shfl_xor)
template <int CTRL>
__device__ __forceinline__ float dpp_add(float v) {
  union { float f; int i; } a, b;
  a.f = v;
  b.i = __builtin_amdgcn_update_dpp(0, a.i, CTRL, 0xf, 0xf, true);
  return a.f + b.f;
}
// full sum over each 16-lane row; result in all 16 lanes
__device__ __forceinline__ float row16_sum(float v) {
  v = dpp_add<0xB1>(v);    // quad_perm [1,0,3,2]  : xor 1
  v = dpp_add<0x4E>(v);    // quad_perm [2,3,0,1]  : xor 2
  v = dpp_add<0x141>(v);   // row_half_mirror      : xor 7 -> sums 8
  v = dpp_add<0x140>(v);   // row_mirror           : xor 15 -> sums 16
  return v;
}

__device__ __forceinline__ void gload_lds16(const unsigned short* g, unsigned short* l) {
  __builtin_amdgcn_global_load_lds((const __attribute__((address_space(1))) unsigned int*)g,
                                   (__attribute__((address_space(3))) unsigned int*)l,
                                   16, 0, 0);
}
__device__ __forceinline__ void gload_lds4(const float* g, unsigned short* l) {
  __builtin_amdgcn_global_load_lds((const __attribute__((address_space(1))) unsigned int*)g,
                                   (__attribute__((address_space(3))) unsigned int*)l,
                                   4, 0, 0);
}

// ---------------- conversions ----------------
__global__ void cvt_bf16(const float* __restrict__ in, unsigned short* __restrict__ out) {
  long i = ((long)blockIdx.x * 256 + threadIdx.x) * 4;
  float4 v = *(const float4*)&in[i];
  unsigned long long p = (unsigned long long)f2bf(v.x)
                       | ((unsigned long long)f2bf(v.y) << 16)
                       | ((unsigned long long)f2bf(v.z) << 32)
                       | ((unsigned long long)f2bf(v.w) << 48);
  *(unsigned long long*)&out[i] = p;
}

__global__ void build_wcat(const float* __restrict__ wqkv, const float* __restrict__ wz,
                           const float* __restrict__ wb, const float* __restrict__ wa,
                           unsigned short* __restrict__ wcat) {
  long idx = (long)blockIdx.x * 256 + threadIdx.x;
  long e = idx * 4;
  long r = e >> 11;
  int cc = (int)(e & 2047);
  unsigned long long p = 0ULL;
  if (r < 12352) {
    const float* src;
    if (r < 8192)       src = wqkv + r * 2048;
    else if (r < 12288) src = wz + (r - 8192) * 2048;
    else if (r < 12320) src = wb + (r - 12288) * 2048;
    else                src = wa + (r - 12320) * 2048;
    float4 v = *(const float4*)&src[cc];
    p = (unsigned long long)f2bf(v.x)
      | ((unsigned long long)f2bf(v.y) << 16)
      | ((unsigned long long)f2bf(v.z) << 32)
      | ((unsigned long long)f2bf(v.w) << 48);
  }
  *(unsigned long long*)&wcat[e] = p;
}

// ---------------- GEMM: C[M,N] = A[M,K] * W[N,K]^T ----------------
template <bool BF16OUT>
__global__ __launch_bounds__(256) void gemm_bt(const unsigned short* __restrict__ A,
                                               const unsigned short* __restrict__ Bw,
                                               void* __restrict__ Cout,
                                               int N, int K) {
  __shared__ unsigned short lds[8192];
  const int tid = threadIdx.x;
  const int wid = tid >> 6;
  const int lane = tid & 63;
  const int m0 = blockIdx.y << 7;
  const int n0 = blockIdx.x << 7;
  const int wr = wid >> 1, wc = wid & 1;

  f32x4 acc[4][4] = {};

  const int srow = (wid << 4) + (lane >> 2);
  const int scol = (lane & 3) << 3;
  const unsigned short* gA0 = A + (long)(m0 + srow) * K + scol;
  const unsigned short* gA1 = A + (long)(m0 + 64 + srow) * K + scol;
  const unsigned short* gB0 = Bw + (long)(n0 + srow) * K + scol;
  const unsigned short* gB1 = Bw + (long)(n0 + 64 + srow) * K + scol;
  unsigned short* ldsA = &lds[wid << 9];
  unsigned short* ldsB = &lds[4096 + (wid << 9)];

  const int lrow = lane & 15;
  const int lk = (lane >> 4) << 3;

  for (int k0 = 0; k0 < K; k0 += 32) {
    __syncthreads();
    gload_lds16(gA0 + k0, ldsA);
    gload_lds16(gA1 + k0, ldsA + 2048);
    gload_lds16(gB0 + k0, ldsB);
    gload_lds16(gB1 + k0, ldsB + 2048);
    __syncthreads();
    short8 av[4], bv[4];
#pragma unroll
    for (int i = 0; i < 4; ++i) {
      av[i] = *(const short8*)&lds[((wr << 6) + (i << 4) + lrow) * 32 + lk];
      bv[i] = *(const short8*)&lds[4096 + ((wc << 6) + (i << 4) + lrow) * 32 + lk];
    }
#pragma unroll
    for (int i = 0; i < 4; ++i)
#pragma unroll
      for (int j = 0; j < 4; ++j)
        acc[i][j] = __builtin_amdgcn_mfma_f32_16x16x32_bf16(av[i], bv[j], acc[i][j], 0, 0, 0);
  }
  const int rbase = m0 + (wr << 6) + ((lane >> 4) << 2);
  const int cbase = n0 + (wc << 6) + (lane & 15);
#pragma unroll
  for (int i = 0; i < 4; ++i)
#pragma unroll
    for (int j = 0; j < 4; ++j)
#pragma unroll
      for (int r = 0; r < 4; ++r) {
        long idx = (long)(rbase + (i << 4) + r) * N + cbase + (j << 4);
        if (BF16OUT) ((unsigned short*)Cout)[idx] = f2bf(acc[i][j][r]);
        else         ((float*)Cout)[idx] = acc[i][j][r];
      }
}

// ---------------- depthwise causal conv1d + silu (8 channels/thread) ----------------
__global__ __launch_bounds__(256) void conv_silu(const unsigned short* __restrict__ C1,
                                                 const float* __restrict__ convw,
                                                 unsigned short* __restrict__ qb,
                                                 unsigned short* __restrict__ kb,
                                                 unsigned short* __restrict__ vb) {
  const int bid = blockIdx.x;             // 512 = cb(4) * tblk(64) * b(2)
  const int cb = bid & 3, tblk = (bid >> 2) & 63, b = bid >> 8;
  const int c0 = cb * 2048 + threadIdx.x * 8;
  float w0[8], w1[8], w2[8], w3[8];
#pragma unroll
  for (int j = 0; j < 8; ++j) {
    float4 wv = *(const float4*)&convw[(c0 + j) * 4];
    w0[j] = wv.x; w1[j] = wv.y; w2[j] = wv.z; w3[j] = wv.w;
  }
  const int t0 = tblk * 32;
  const long rowbase = ((long)b * TT) * N1PAD + c0;
  float x0[8], x1[8], x2[8];
#pragma unroll
  for (int j = 0; j < 8; ++j) { x0[j] = 0.f; x1[j] = 0.f; x2[j] = 0.f; }
  if (t0 >= 1) { ushort8 r = *(const ushort8*)&C1[rowbase + (long)(t0 - 1) * N1PAD];
#pragma unroll
    for (int j = 0; j < 8; ++j) x2[j] = bf2f(r[j]); }
  if (t0 >= 2) { ushort8 r = *(const ushort8*)&C1[rowbase + (long)(t0 - 2) * N1PAD];
#pragma unroll
    for (int j = 0; j < 8; ++j) x1[j] = bf2f(r[j]); }
  if (t0 >= 3) { ushort8 r = *(const ushort8*)&C1[rowbase + (long)(t0 - 3) * N1PAD];
#pragma unroll
    for (int j = 0; j < 8; ++j) x0[j] = bf2f(r[j]); }

  for (int t = t0; t < t0 + 32; ++t) {
    ushort8 rr = *(const ushort8*)&C1[rowbase + (long)t * N1PAD];
    ushort8 outp;
#pragma unroll
    for (int j = 0; j < 8; ++j) {
      float x3 = bf2f(rr[j]);
      float y = w0[j] * x0[j] + w1[j] * x1[j] + w2[j] * x2[j] + w3[j] * x3;
      y = y / (1.f + __expf(-y));
      outp[j] = f2bf(y);
      x0[j] = x1[j]; x1[j] = x2[j]; x2[j] = x3;
    }
    long m = (long)b * TT + t;
    if (cb == 0)      *(ushort8*)&qb[m * 2048 + threadIdx.x * 8] = outp;
    else if (cb == 1) *(ushort8*)&kb[m * 2048 + threadIdx.x * 8] = outp;
    else              *(ushort8*)&vb[m * 4096 + (cb - 2) * 2048 + threadIdx.x * 8] = outp;
  }
}

// ---------------- g (decay) and beta ----------------
__global__ void gbeta(const unsigned short* __restrict__ C1, const float* __restrict__ Alog,
                      const float* __restrict__ dtb, float* __restrict__ egb, float* __restrict__ betab) {
  int idx = blockIdx.x * 256 + threadIdx.x;   // < 131072
  int m = idx >> 5, h = idx & 31;
  float a = bf2f(C1[(long)m * N1PAD + 12320 + h]);
  float bl = bf2f(C1[(long)m * N1PAD + 12288 + h]);
  float xsp = a + dtb[h];
  float sp = (xsp > 20.f) ? xsp : log1pf(expf(xsp));
  egb[idx] = expf(-expf(Alog[h]) * sp);
  betab[idx] = 1.f / (1.f + expf(-bl));
}

// ---------------- l2 norm over DK=128 (one wave per head) ----------------
__global__ __launch_bounds__(256) void l2norm(unsigned short* __restrict__ buf, float scale) {
  int hid = blockIdx.x * 4 + (threadIdx.x >> 6);
  int lane = threadIdx.x & 63;
  long off = (long)hid * 128 + lane * 2;
  unsigned int u = *(unsigned int*)&buf[off];
  float a = bf2f((unsigned short)(u & 0xffff));
  float c = bf2f((unsigned short)(u >> 16));
  float ss = a * a + c * c;
#pragma unroll
  for (int mm = 1; mm < 64; mm <<= 1) ss += __shfl_xor(ss, mm);
  float sc = scale / fmaxf(sqrtf(ss), 1e-12f);
  unsigned int pk = (unsigned int)f2bf(a * sc) | ((unsigned int)f2bf(c * sc) << 16);
  *(unsigned int*)&buf[off] = pk;
}

// ---------------- gated delta rule scan (16 lanes/col x 8 S-regs, DPP reduce) ----------------
// LDS per buffer (8832 ush = 17664 B):
//   k  [CHUNK][128] @ 0        (8192 B = 2 rounds x 4 waves x 1024 B)
//   q  [CHUNK][128] @ 4096 ush
//   v  [CHUNK][16]  @ 8192 ush (1024 B = wave 2)
//   g,b f32 [32+32] @ 8704 ush (256 B = wave 3)
__global__ __launch_bounds__(256) void scan_kernel(const unsigned short* __restrict__ qb,
                                                   const unsigned short* __restrict__ kb,
                                                   const unsigned short* __restrict__ vb,
                                                   const float* __restrict__ egb,
                                                   const float* __restrict__ betab,
                                                   unsigned short* __restrict__ ob) {
  const int bi = blockIdx.x;   // 512 = vc(8) * h(32) * b(2)
  const int vc = bi & 7, h = (bi >> 3) & 31, b = bi >> 8;
  const int hk = h >> 1;
  const int tid = threadIdx.x;
  const int wid = tid >> 6, lane = tid & 63;
  const int col = tid >> 4, ks = tid & 15;   // 16 cols/block, 16 lanes/col

  __shared__ unsigned short sl[2][8832];

  float S[8];
#pragma unroll
  for (int i = 0; i < 8; ++i) S[i] = 0.f;

  const long kqoff = ((long)b * TT) * 2048 + hk * 128;
  const long voff  = ((long)b * TT) * 4096 + h * 128 + vc * 16;
  const long goff  = ((long)b * TT) * 32 + h;

  // global_load_lds writes lane l's payload at lds_base + l*size (linear);
  // per-lane global addresses must follow the same linear order.
  auto stage = [&](int bf, int t0) {
    unsigned short* base = sl[bf];
#pragma unroll
    for (int r = 0; r < 2; ++r) {
      int i = r * 256 + tid;                 // dest byte = i*16 within region
      int step = i >> 4, frag = i & 15;
      gload_lds16(kb + kqoff + (long)(t0 + step) * 2048 + frag * 8,
                  base + (r * 4 + wid) * 512);
      gload_lds16(qb + kqoff + (long)(t0 + step) * 2048 + frag * 8,
                  base + 4096 + (r * 4 + wid) * 512);
    }
    if (wid == 2) {
      // v: 1024 B; dest byte = lane*16 = (lane>>1)*32 + (lane&1)*16
      int step = lane >> 1, frag = lane & 1;
      gload_lds16(vb + voff + (long)(t0 + step) * 4096 + frag * 8,
                  base + 8192);
    } else if (wid == 3) {
      // g,b: 256 B; dest byte = lane*4
      const float* gp = (lane < 32) ? (egb + goff + (long)(t0 + lane) * 32)
                                    : (betab + goff + (long)(t0 + lane - 32) * 32);
      gload_lds4(gp, base + 8704);
    }
  };

  stage(0, 0);
  __syncthreads();

  const int kqo = ks * 8;         // ushort offset of this thread's fragment within a row
  int bf = 0;
  for (int c = 0; c < TT / CHUNK; ++c) {
    if (c + 1 < TT / CHUNK) stage(bf ^ 1, (c + 1) * CHUNK);
    const unsigned short* base = sl[bf];
    const float* gf = (const float*)(base + 8704);
    long obase = ((long)(b * TT + c * CHUNK) * 32 + h) * 128 + vc * 16 + col;
#pragma unroll 4
    for (int s = 0; s < CHUNK; ++s) {
      uint4 ka = *(const uint4*)(base + s * 128 + kqo);
      uint4 qa = *(const uint4*)(base + 4096 + s * 128 + kqo);
      float eg = gf[s];
      float bt = gf[32 + s];
      float vv = bf2f(base[8192 + s * 16 + col]);
      float kf[8], qf[8];
#define UNP(u4, f)                                                      \
      f[0]=bitsf((u4).x<<16); f[1]=bitsf((u4).x&0xffff0000u);           \
      f[2]=bitsf((u4).y<<16); f[3]=bitsf((u4).y&0xffff0000u);           \
      f[4]=bitsf((u4).z<<16); f[5]=bitsf((u4).z&0xffff0000u);           \
      f[6]=bitsf((u4).w<<16); f[7]=bitsf((u4).w&0xffff0000u);
      UNP(ka, kf) UNP(qa, qf)
#undef UNP
      // kv_raw = dot(k, S) with UNDECAYED S (decay folded in afterwards:
      // k.(eg*S) = eg*(k.S)); 4-way split chains + 4-stage DPP reduce.
      float kv0 = kf[0] * S[0], kv1 = kf[1] * S[1], kv2 = kf[2] * S[2], kv3 = kf[3] * S[3];
      kv0 = fmaf(kf[4], S[4], kv0);
      kv1 = fmaf(kf[5], S[5], kv1);
      kv2 = fmaf(kf[6], S[6], kv2);
      kv3 = fmaf(kf[7], S[7], kv3);
      float kvr = (kv0 + kv1) + (kv2 + kv3);
      kvr = row16_sum(kvr);
      // off-critical-path: decayed state and bv coefficients
      float Sd[8];
#pragma unroll
      for (int i = 0; i < 8; ++i) Sd[i] = eg * S[i];
      float btv = bt * vv;
      float nbe = -bt * eg;
      float bv = fmaf(nbe, kvr, btv);        // = bt*(vv - eg*kv_raw)
      // S = eg*S + k*bv ;  o = dot(q, S_new)
      float o0, o1, o2, o3;
      S[0] = fmaf(kf[0], bv, Sd[0]); o0 = qf[0] * S[0];
      S[1] = fmaf(kf[1], bv, Sd[1]); o1 = qf[1] * S[1];
      S[2] = fmaf(kf[2], bv, Sd[2]); o2 = qf[2] * S[2];
      S[3] = fmaf(kf[3], bv, Sd[3]); o3 = qf[3] * S[3];
      S[4] = fmaf(kf[4], bv, Sd[4]); o0 = fmaf(qf[4], S[4], o0);
      S[5] = fmaf(kf[5], bv, Sd[5]); o1 = fmaf(qf[5], S[5], o1);
      S[6] = fmaf(kf[6], bv, Sd[6]); o2 = fmaf(qf[6], S[6], o2);
      S[7] = fmaf(kf[7], bv, Sd[7]); o3 = fmaf(qf[7], S[7], o3);
      float o = (o0 + o1) + (o2 + o3);
      o = row16_sum(o);
      if (ks == 0) ob[obase + (long)s * 4096] = f2bf(o);
    }
    __syncthreads();
    bf ^= 1;
  }
}

// ---------------- gated RMSNorm * silu(z) -> bf16 ----------------
__global__ __launch_bounds__(256) void norm_silu(const unsigned short* __restrict__ ob,
                                                 const unsigned short* __restrict__ C1,
                                                 const float* __restrict__ nw,
                                                 unsigned short* __restrict__ nrm) {
  int unit = blockIdx.x * 4 + (threadIdx.x >> 6);   // m*32+h
  int lane = threadIdx.x & 63;
  int m = unit >> 5, h = unit & 31;
  unsigned int uo = *(const unsigned int*)&ob[(long)unit * 128 + lane * 2];
  float o0 = bf2f((unsigned short)(uo & 0xffff));
  float o1 = bf2f((unsigned short)(uo >> 16));
  float ss = o0 * o0 + o1 * o1;
#pragma unroll
  for (int mm = 1; mm < 64; mm <<= 1) ss += __shfl_xor(ss, mm);
  float rs = rsqrtf(ss * (1.0f / 128.0f) + 1e-6f);
  unsigned int uz = *(const unsigned int*)&C1[(long)m * N1PAD + 8192 + h * 128 + lane * 2];
  float z0 = bf2f((unsigned short)(uz & 0xffff));
  float z1 = bf2f((unsigned short)(uz >> 16));
  float s0 = z0 / (1.f + expf(-z0));
  float s1 = z1 / (1.f + expf(-z1));
  float r0 = o0 * rs * nw[lane * 2] * s0;
  float r1 = o1 * rs * nw[lane * 2 + 1] * s1;
  unsigned int pk = (unsigned int)f2bf(r0) | ((unsigned int)f2bf(r1) << 16);
  *(unsigned int*)&nrm[(long)unit * 128 + lane * 2] = pk;
}

extern "C" void kernel_launch(void* const* d_in, const int* in_sizes, int n_in,
                              void* d_out, int out_size, void* d_ws, size_t ws_size,
                              hipStream_t stream) {
  const float* x    = (const float*)d_in[0];
  const float* Wqkv = (const float*)d_in[2];
  const float* Wz   = (const float*)d_in[3];
  const float* Wb   = (const float*)d_in[4];
  const float* Wa   = (const float*)d_in[5];
  const float* convw= (const float*)d_in[6];
  const float* dtb  = (const float*)d_in[7];
  const float* Alog = (const float*)d_in[8];
  const float* nw   = (const float*)d_in[9];
  const float* Wout = (const float*)d_in[10];
  float* out = (float*)d_out;

  char* ws = (char*)d_ws;
  const size_t OFF_C1    = 0;                    // bf16 [4096][12416]
  const size_t OFF_XB    = 101711872;            // bf16 [4096][2048]
  const size_t OFF_WCAT  = 118489088;            // bf16 [12416][2048]
  const size_t OFF_QB    = OFF_XB;               // over xb (post-GEMM1)
  const size_t OFF_KB    = 118489088;            // over wcat
  const size_t OFF_VB    = 135266304;            // over wcat
  const size_t OFF_EG    = 169345024;            // f32  [4096][32]
  const size_t OFF_BE    = 169869312;
  const size_t OFF_OB    = 170393600;            // bf16 [4096][32][128]
  const size_t OFF_NRM   = OFF_QB;               // over qb+kb (post-scan)
  const size_t OFF_WOUTB = OFF_VB;               // over vb (post-scan)

  unsigned short* C1    = (unsigned short*)(ws + OFF_C1);
  unsigned short* xb    = (unsigned short*)(ws + OFF_XB);
  unsigned short* wcat  = (unsigned short*)(ws + OFF_WCAT);
  unsigned short* qb    = (unsigned short*)(ws + OFF_QB);
  unsigned short* kb    = (unsigned short*)(ws + OFF_KB);
  unsigned short* vb    = (unsigned short*)(ws + OFF_VB);
  float*          egb   = (float*)(ws + OFF_EG);
  float*          betab = (float*)(ws + OFF_BE);
  unsigned short* ob    = (unsigned short*)(ws + OFF_OB);
  unsigned short* nrm   = (unsigned short*)(ws + OFF_NRM);
  unsigned short* woutb = (unsigned short*)(ws + OFF_WOUTB);
  (void)ws_size; (void)in_sizes; (void)n_in; (void)out_size;

  cvt_bf16<<<8192, 256, 0, stream>>>(x, xb);
  build_wcat<<<24832, 256, 0, stream>>>(Wqkv, Wz, Wb, Wa, wcat);
  gemm_bt<true><<<dim3(N1PAD / 128, M_ROWS / 128), 256, 0, stream>>>(xb, wcat, C1, N1PAD, 2048);
  conv_silu<<<512, 256, 0, stream>>>(C1, convw, qb, kb, vb);
  gbeta<<<512, 256, 0, stream>>>(C1, Alog, dtb, egb, betab);
  l2norm<<<16384, 256, 0, stream>>>(qb, 0.08838834764831845f);   // fold DK^-0.5 into q
  l2norm<<<16384, 256, 0, stream>>>(kb, 1.0f);
  scan_kernel<<<512, 256, 0, stream>>>(qb, kb, vb, egb, betab, ob);
  cvt_bf16<<<8192, 256, 0, stream>>>(Wout, woutb);
  norm_silu<<<32768, 256, 0, stream>>>(ob, C1, nw, nrm);
  gemm_bt<false><<<dim3(2048 / 128, M_ROWS / 128), 256, 0, stream>>>(nrm, woutb, out, 2048, 4096);
}

// Round 7
// 992.785 us; speedup vs baseline: 1.5074x; 1.1805x over previous
//
#include <hip/hip_runtime.h>

// dims
#define BB 2
#define TT 2048
#define HID 2048
#define HK 16
#define HV 32
#define DK 128
#define DV 128
#define KW 4
#define KEY_DIM 2048
#define VAL_DIM 4096
#define CONV_DIM 8192
#define N1PAD 12416     // 12352 padded to 128
#define M_ROWS 4096     // B*T
#define CC 64           // scan chunk length

typedef __attribute__((ext_vector_type(8))) short short8;
typedef __attribute__((ext_vector_type(8))) unsigned short ushort8;
typedef __attribute__((ext_vector_type(4))) float f32x4;

__device__ __forceinline__ unsigned short f2bf(float f) {
  union { float f; unsigned int u; } v; v.f = f;
  unsigned int r = v.u + 0x7FFFu + ((v.u >> 16) & 1u);
  return (unsigned short)(r >> 16);
}
__device__ __forceinline__ float bf2f(unsigned short u) {
  union { unsigned int u; float f; } v; v.u = ((unsigned int)u) << 16; return v.f;
}

// pure-VALU cross-lane add via DPP
template <int CTRL>
__device__ __forceinline__ float dpp_add(float v) {
  union { float f; int i; } a, b;
  a.f = v;
  b.i = __builtin_amdgcn_update_dpp(0, a.i, CTRL, 0xf, 0xf, true);
  return a.f + b.f;
}
__device__ __forceinline__ float row16_sum(float v) {
  v = dpp_add<0xB1>(v); v = dpp_add<0x4E>(v);
  v = dpp_add<0x141>(v); v = dpp_add<0x140>(v);
  return v;
}
__device__ __forceinline__ float row8_sum(float v) {
  v = dpp_add<0xB1>(v); v = dpp_add<0x4E>(v); v = dpp_add<0x141>(v);
  return v;
}

__device__ __forceinline__ void gload_lds16(const unsigned short* g, unsigned short* l) {
  __builtin_amdgcn_global_load_lds((const __attribute__((address_space(1))) unsigned int*)g,
                                   (__attribute__((address_space(3))) unsigned int*)l,
                                   16, 0, 0);
}
__device__ __forceinline__ void gload_lds4(const float* g, unsigned short* l) {
  __builtin_amdgcn_global_load_lds((const __attribute__((address_space(1))) unsigned int*)g,
                                   (__attribute__((address_space(3))) unsigned int*)l,
                                   4, 0, 0);
}

// swizzled LDS bf16 reads: row-major rows of 256B (sh=8) or 128B (sh=7); byte ^= ((row&7)<<4)
__device__ __forceinline__ short8 ldswz8(const char* base, int row, int e16) {
  int L = (row << 8) + (e16 << 1);
  return *(const short8*)(base + (L ^ ((row & 7) << 4)));
}
__device__ __forceinline__ short8 ldswz7(const char* base, int row, int e16) {
  int L = (row << 7) + (e16 << 1);
  return *(const short8*)(base + (L ^ ((row & 7) << 4)));
}

// ---------------- conversions ----------------
__global__ void cvt_bf16(const float* __restrict__ in, unsigned short* __restrict__ out) {
  long i = ((long)blockIdx.x * 256 + threadIdx.x) * 4;
  float4 v = *(const float4*)&in[i];
  unsigned long long p = (unsigned long long)f2bf(v.x)
                       | ((unsigned long long)f2bf(v.y) << 16)
                       | ((unsigned long long)f2bf(v.z) << 32)
                       | ((unsigned long long)f2bf(v.w) << 48);
  *(unsigned long long*)&out[i] = p;
}

__global__ void build_wcat(const float* __restrict__ wqkv, const float* __restrict__ wz,
                           const float* __restrict__ wb, const float* __restrict__ wa,
                           unsigned short* __restrict__ wcat) {
  long idx = (long)blockIdx.x * 256 + threadIdx.x;
  long e = idx * 4;
  long r = e >> 11;
  int cc = (int)(e & 2047);
  unsigned long long p = 0ULL;
  if (r < 12352) {
    const float* src;
    if (r < 8192)       src = wqkv + r * 2048;
    else if (r < 12288) src = wz + (r - 8192) * 2048;
    else if (r < 12320) src = wb + (r - 12288) * 2048;
    else                src = wa + (r - 12320) * 2048;
    float4 v = *(const float4*)&src[cc];
    p = (unsigned long long)f2bf(v.x)
      | ((unsigned long long)f2bf(v.y) << 16)
      | ((unsigned long long)f2bf(v.z) << 32)
      | ((unsigned long long)f2bf(v.w) << 48);
  }
  *(unsigned long long*)&wcat[e] = p;
}

// ---------------- GEMM: C[M,N] = A[M,K] * W[N,K]^T ----------------
template <bool BF16OUT>
__global__ __launch_bounds__(256) void gemm_bt(const unsigned short* __restrict__ A,
                                               const unsigned short* __restrict__ Bw,
                                               void* __restrict__ Cout,
                                               int N, int K) {
  __shared__ unsigned short lds[8192];
  const int tid = threadIdx.x;
  const int wid = tid >> 6;
  const int lane = tid & 63;
  const int m0 = blockIdx.y << 7;
  const int n0 = blockIdx.x << 7;
  const int wr = wid >> 1, wc = wid & 1;

  f32x4 acc[4][4] = {};

  const int srow = (wid << 4) + (lane >> 2);
  const int scol = (lane & 3) << 3;
  const unsigned short* gA0 = A + (long)(m0 + srow) * K + scol;
  const unsigned short* gA1 = A + (long)(m0 + 64 + srow) * K + scol;
  const unsigned short* gB0 = Bw + (long)(n0 + srow) * K + scol;
  const unsigned short* gB1 = Bw + (long)(n0 + 64 + srow) * K + scol;
  unsigned short* ldsA = &lds[wid << 9];
  unsigned short* ldsB = &lds[4096 + (wid << 9)];

  const int lrow = lane & 15;
  const int lk = (lane >> 4) << 3;

  for (int k0 = 0; k0 < K; k0 += 32) {
    __syncthreads();
    gload_lds16(gA0 + k0, ldsA);
    gload_lds16(gA1 + k0, ldsA + 2048);
    gload_lds16(gB0 + k0, ldsB);
    gload_lds16(gB1 + k0, ldsB + 2048);
    __syncthreads();
    short8 av[4], bv[4];
#pragma unroll
    for (int i = 0; i < 4; ++i) {
      av[i] = *(const short8*)&lds[((wr << 6) + (i << 4) + lrow) * 32 + lk];
      bv[i] = *(const short8*)&lds[4096 + ((wc << 6) + (i << 4) + lrow) * 32 + lk];
    }
#pragma unroll
    for (int i = 0; i < 4; ++i)
#pragma unroll
      for (int j = 0; j < 4; ++j)
        acc[i][j] = __builtin_amdgcn_mfma_f32_16x16x32_bf16(av[i], bv[j], acc[i][j], 0, 0, 0);
  }
  const int rbase = m0 + (wr << 6) + ((lane >> 4) << 2);
  const int cbase = n0 + (wc << 6) + (lane & 15);
#pragma unroll
  for (int i = 0; i < 4; ++i)
#pragma unroll
    for (int j = 0; j < 4; ++j)
#pragma unroll
      for (int r = 0; r < 4; ++r) {
        long idx = (long)(rbase + (i << 4) + r) * N + cbase + (j << 4);
        if (BF16OUT) ((unsigned short*)Cout)[idx] = f2bf(acc[i][j][r]);
        else         ((float*)Cout)[idx] = acc[i][j][r];
      }
}

// ---------------- depthwise causal conv1d + silu ----------------
__global__ __launch_bounds__(256) void conv_silu(const unsigned short* __restrict__ C1,
                                                 const float* __restrict__ convw,
                                                 unsigned short* __restrict__ qb,
                                                 unsigned short* __restrict__ kb,
                                                 unsigned short* __restrict__ vb) {
  const int bid = blockIdx.x;             // 512 = cb(4) * tblk(64) * b(2)
  const int cb = bid & 3, tblk = (bid >> 2) & 63, b = bid >> 8;
  const int c0 = cb * 2048 + threadIdx.x * 8;
  float w0[8], w1[8], w2[8], w3[8];
#pragma unroll
  for (int j = 0; j < 8; ++j) {
    float4 wv = *(const float4*)&convw[(c0 + j) * 4];
    w0[j] = wv.x; w1[j] = wv.y; w2[j] = wv.z; w3[j] = wv.w;
  }
  const int t0 = tblk * 32;
  const long rowbase = ((long)b * TT) * N1PAD + c0;
  float x0[8], x1[8], x2[8];
#pragma unroll
  for (int j = 0; j < 8; ++j) { x0[j] = 0.f; x1[j] = 0.f; x2[j] = 0.f; }
  if (t0 >= 1) { ushort8 r = *(const ushort8*)&C1[rowbase + (long)(t0 - 1) * N1PAD];
#pragma unroll
    for (int j = 0; j < 8; ++j) x2[j] = bf2f(r[j]); }
  if (t0 >= 2) { ushort8 r = *(const ushort8*)&C1[rowbase + (long)(t0 - 2) * N1PAD];
#pragma unroll
    for (int j = 0; j < 8; ++j) x1[j] = bf2f(r[j]); }
  if (t0 >= 3) { ushort8 r = *(const ushort8*)&C1[rowbase + (long)(t0 - 3) * N1PAD];
#pragma unroll
    for (int j = 0; j < 8; ++j) x0[j] = bf2f(r[j]); }

  for (int t = t0; t < t0 + 32; ++t) {
    ushort8 rr = *(const ushort8*)&C1[rowbase + (long)t * N1PAD];
    ushort8 outp;
#pragma unroll
    for (int j = 0; j < 8; ++j) {
      float x3 = bf2f(rr[j]);
      float y = w0[j] * x0[j] + w1[j] * x1[j] + w2[j] * x2[j] + w3[j] * x3;
      y = y / (1.f + __expf(-y));
      outp[j] = f2bf(y);
      x0[j] = x1[j]; x1[j] = x2[j]; x2[j] = x3;
    }
    long m = (long)b * TT + t;
    if (cb == 0)      *(ushort8*)&qb[m * 2048 + threadIdx.x * 8] = outp;
    else if (cb == 1) *(ushort8*)&kb[m * 2048 + threadIdx.x * 8] = outp;
    else              *(ushort8*)&vb[m * 4096 + (cb - 2) * 2048 + threadIdx.x * 8] = outp;
  }
}

// ---------------- raw g (log decay) and beta ----------------
__global__ void gbeta(const unsigned short* __restrict__ C1, const float* __restrict__ Alog,
                      const float* __restrict__ dtb, float* __restrict__ graw, float* __restrict__ betab) {
  int idx = blockIdx.x * 256 + threadIdx.x;   // < 131072
  int m = idx >> 5, h = idx & 31;
  float a = bf2f(C1[(long)m * N1PAD + 12320 + h]);
  float bl = bf2f(C1[(long)m * N1PAD + 12288 + h]);
  float xsp = a + dtb[h];
  float sp = (xsp > 20.f) ? xsp : log1pf(expf(xsp));
  graw[idx] = -expf(Alog[h]) * sp;            // raw g (negative), NOT exp(g)
  betab[idx] = 1.f / (1.f + expf(-bl));
}

// ---------------- l2 norm over DK=128 ----------------
__global__ __launch_bounds__(256) void l2norm(unsigned short* __restrict__ buf, float scale) {
  int hid = blockIdx.x * 4 + (threadIdx.x >> 6);
  int lane = threadIdx.x & 63;
  long off = (long)hid * 128 + lane * 2;
  unsigned int u = *(unsigned int*)&buf[off];
  float a = bf2f((unsigned short)(u & 0xffff));
  float c = bf2f((unsigned short)(u >> 16));
  float ss = a * a + c * c;
#pragma unroll
  for (int mm = 1; mm < 64; mm <<= 1) ss += __shfl_xor(ss, mm);
  float sc = scale / fmaxf(sqrtf(ss), 1e-12f);
  unsigned int pk = (unsigned int)f2bf(a * sc) | ((unsigned int)f2bf(c * sc) << 16);
  *(unsigned int*)&buf[off] = pk;
}

// ---------------- chunked gated delta rule scan (MFMA WY-form) ----------------
// LDS map (bytes):
#define OFF_K   0          // [64][128] bf16 swz (per input buffer)
#define OFF_Q   16384
#define OFF_V   32768      // [64][32] bf16 linear
#define OFF_G   36864      // [64] f32
#define OFF_B2  37120      // [64] f32
#define INSZ    37376
#define OFF_KT  74752      // [128][64] bf16 swz
#define OFF_SH  91136      // St hi [32][128] bf16 swz
#define OFF_SL  99328      // St lo
#define OFF_A2  107520     // [64][8][8] f32 (A2[t][r][j] = A[t][8j+r])
#define OFF_MM  123904     // M [64][64] bf16 swz
#define OFF_BT  132096     // Bt [32][64] bf16 swz
#define OFF_BT2 136192
#define OFF_X   140288     // [64][32] f32
#define OFF_CS  148480
#define OFF_EXC 148736
#define OFF_ECT 148992
#define SMEM_SZ 149248

__global__ __launch_bounds__(256) void chunk_scan(const unsigned short* __restrict__ qb,
                                                  const unsigned short* __restrict__ kb,
                                                  const unsigned short* __restrict__ vb,
                                                  const float* __restrict__ graw,
                                                  const float* __restrict__ betab,
                                                  unsigned short* __restrict__ ob) {
  extern __shared__ char smem[];
  // XCD-grouped decode: blocks w with same (w&31) share (b,hk) k/q data -> same XCD L2
  const int w = blockIdx.x;
  const int rdec = w >> 5, gdec = w & 31;
  const int bat = gdec >> 4, hk = gdec & 15;
  const int h = hk * 2 + (rdec >> 2), vc = rdec & 3;
  const int tid = threadIdx.x, wid = tid >> 6, lane = tid & 63;
  const int lr = lane & 15, lq = lane >> 4;

  const long kqoff = ((long)bat * TT) * 2048 + hk * 128;
  const long voff  = ((long)bat * TT) * 4096 + h * 128 + vc * 32;
  const long goff  = ((long)bat * TT) * 32 + h;

  f32x4 Smast[4] = {};     // S master f32, D-layout of MFMA-5 (rows=vc, cols=dk)
  float oq[8];

  auto stagec = [&](char* inb2, int t0c) {
    // k,q: 4 x 16B per thread; linear dest => inverse-swizzled global source
#pragma unroll
    for (int it = 0; it < 4; ++it) {
      int i = it * 256 + tid;
      int rowk = i >> 4;
      int L = (i << 4) ^ ((rowk & 7) << 4);
      int srcoff = (L & 255) >> 1;
      long grow = (long)(t0c + rowk) * 2048 + srcoff;
      gload_lds16(kb + kqoff + grow, (unsigned short*)(inb2 + OFF_K) + it * 2048 + wid * 512);
      gload_lds16(qb + kqoff + grow, (unsigned short*)(inb2 + OFF_Q) + it * 2048 + wid * 512);
    }
    { // v: 1 x 16B per thread, linear
      int i = tid;
      gload_lds16(vb + voff + (long)(t0c + (i >> 2)) * 4096 + (i & 3) * 8,
                  (unsigned short*)(inb2 + OFF_V) + wid * 512);
    }
    if (wid == 3) gload_lds4(graw  + goff + (long)(t0c + lane) * 32, (unsigned short*)(inb2 + OFF_G));
    if (wid == 2) gload_lds4(betab + goff + (long)(t0c + lane) * 32, (unsigned short*)(inb2 + OFF_B2));
  };

  // prologue: stage chunk 0, zero St
  stagec(smem, 0);
#pragma unroll
  for (int z = 0; z < 4; ++z)
    *(f32x4*)(smem + OFF_SH + tid * 64 + z * 16) = (f32x4){0.f, 0.f, 0.f, 0.f};
  asm volatile("s_waitcnt vmcnt(0)" ::: "memory");
  __syncthreads();

  for (int ct = 0; ct < TT / CC; ++ct) {
    char* inb = smem + (ct & 1) * INSZ;
    // ---- T1: prefetch next chunk; wave0 cumsum; waves1-3 kT transpose ----
    if (ct + 1 < TT / CC) stagec(smem + ((ct + 1) & 1) * INSZ, (ct + 1) * CC);
    if (wid == 0) {
      float gv = ((const float*)(inb + OFF_G))[lane];
#pragma unroll
      for (int off = 1; off < 64; off <<= 1) {
        float n = __shfl_up(gv, off);
        if (lane >= off) gv += n;
      }
      ((float*)(smem + OFF_CS))[lane] = gv;
    } else {
      int bt_ = tid - 64;
#pragma unroll
      for (int it = 0; it < 3; ++it) {
        int idx = it * 192 + bt_;
        if (idx < 512) {
          int tp = idx >> 4, dkb = idx & 15;
          short8 r0 = ldswz8(inb + OFF_K, 2 * tp, dkb * 8);
          short8 r1 = ldswz8(inb + OFF_K, 2 * tp + 1, dkb * 8);
#pragma unroll
          for (int e = 0; e < 8; ++e) {
            int dk = dkb * 8 + e;
            unsigned int pk = (unsigned int)(unsigned short)r0[e]
                            | ((unsigned int)(unsigned short)r1[e] << 16);
            int Lk = (dk << 7) + (tp << 2);
            *(unsigned int*)(smem + OFF_KT + (Lk ^ ((dk & 7) << 4))) = pk;
          }
        }
      }
    }
    __syncthreads();

    // ---- T2: exp tables + the 4 front MFMAs ----
    if (tid < 64) {
      const float* csp = (const float*)(smem + OFF_CS);
      float cst = csp[tid], csC = csp[63];
      ((float*)(smem + OFF_EXC))[tid] = __expf(cst);
      ((float*)(smem + OFF_ECT))[tid] = __expf(csC - cst);
    }
    f32x4 aKK[4] = {}, aQK[4] = {}, aKS[2] = {}, aQS[2] = {};
#pragma unroll
    for (int kk = 0; kk < 4; ++kk) {
      int ke = kk * 32 + lq * 8;
      short8 avk = ldswz8(inb + OFF_K, 16 * wid + lr, ke);
      short8 avq = ldswz8(inb + OFF_Q, 16 * wid + lr, ke);
      short8 bvk[4];
#pragma unroll
      for (int tc = 0; tc < 4; ++tc) bvk[tc] = ldswz8(inb + OFF_K, 16 * tc + lr, ke);
      short8 bH0 = ldswz8(smem + OFF_SH, lr, ke);
      short8 bH1 = ldswz8(smem + OFF_SH, 16 + lr, ke);
      short8 bL0 = ldswz8(smem + OFF_SL, lr, ke);
      short8 bL1 = ldswz8(smem + OFF_SL, 16 + lr, ke);
#pragma unroll
      for (int tc = 0; tc < 4; ++tc) {
        aKK[tc] = __builtin_amdgcn_mfma_f32_16x16x32_bf16(avk, bvk[tc], aKK[tc], 0, 0, 0);
        aQK[tc] = __builtin_amdgcn_mfma_f32_16x16x32_bf16(avq, bvk[tc], aQK[tc], 0, 0, 0);
      }
      aKS[0] = __builtin_amdgcn_mfma_f32_16x16x32_bf16(avk, bH0, aKS[0], 0, 0, 0);
      aKS[0] = __builtin_amdgcn_mfma_f32_16x16x32_bf16(avk, bL0, aKS[0], 0, 0, 0);
      aKS[1] = __builtin_amdgcn_mfma_f32_16x16x32_bf16(avk, bH1, aKS[1], 0, 0, 0);
      aKS[1] = __builtin_amdgcn_mfma_f32_16x16x32_bf16(avk, bL1, aKS[1], 0, 0, 0);
      aQS[0] = __builtin_amdgcn_mfma_f32_16x16x32_bf16(avq, bH0, aQS[0], 0, 0, 0);
      aQS[0] = __builtin_amdgcn_mfma_f32_16x16x32_bf16(avq, bL0, aQS[0], 0, 0, 0);
      aQS[1] = __builtin_amdgcn_mfma_f32_16x16x32_bf16(avq, bH1, aQS[1], 0, 0, 0);
      aQS[1] = __builtin_amdgcn_mfma_f32_16x16x32_bf16(avq, bL1, aQS[1], 0, 0, 0);
    }
    __syncthreads();

    // ---- T3: scale + write A2 (f32), M (bf16), X (f32); oq kept in regs ----
    {
      const float* csp  = (const float*)(smem + OFF_CS);
      const float* excp = (const float*)(smem + OFF_EXC);
      const float* betp = (const float*)(inb + OFF_B2);
      const unsigned short* vp = (const unsigned short*)(inb + OFF_V);
      float cst[4], bt4[4], ext[4];
#pragma unroll
      for (int j = 0; j < 4; ++j) {
        int t = 16 * wid + lq * 4 + j;
        cst[j] = csp[t]; bt4[j] = betp[t]; ext[j] = excp[t];
      }
#pragma unroll
      for (int tc = 0; tc < 4; ++tc) {
        int i = 16 * tc + lr;
        float csi = csp[i];
#pragma unroll
        for (int j = 0; j < 4; ++j) {
          int t = 16 * wid + lq * 4 + j;
          float e = __expf(cst[j] - csi);
          float av = (i < t) ? bt4[j] * e * aKK[tc][j] : 0.f;
          ((float*)(smem + OFF_A2))[t * 64 + (i & 7) * 8 + (i >> 3)] = av;
          float mv = (i <= t) ? e * aQK[tc][j] : 0.f;
          int Lm = (t << 7) + (i << 1);
          *(unsigned short*)(smem + OFF_MM + (Lm ^ ((t & 7) << 4))) = f2bf(mv);
        }
      }
#pragma unroll
      for (int nt = 0; nt < 2; ++nt) {
        int vcl = nt * 16 + lr;
#pragma unroll
        for (int j = 0; j < 4; ++j) {
          int t = 16 * wid + lq * 4 + j;
          float vvv = bf2f(vp[t * 32 + vcl]);
          float x = bt4[j] * (vvv - ext[j] * aKS[nt][j]);
          ((float*)(smem + OFF_X))[t * 32 + vcl] = x;
          oq[nt * 4 + j] = ext[j] * aQS[nt][j];
        }
      }
    }
    __syncthreads();

    // ---- T4: forward substitution (I+A)B = X, serial over 64 steps ----
    {
      const float* A2p  = (const float*)(smem + OFF_A2);
      const float* Xp   = (const float*)(smem + OFF_X);
      const float* ectp = (const float*)(smem + OFF_ECT);
      const int col = tid >> 3, rr = tid & 7;
      float bbv[8] = {0.f, 0.f, 0.f, 0.f, 0.f, 0.f, 0.f, 0.f};
#pragma unroll
      for (int t = 0; t < 64; ++t) {
        float4 a0 = *(const float4*)(A2p + t * 64 + rr * 8);
        float4 a1 = *(const float4*)(A2p + t * 64 + rr * 8 + 4);
        float sA = fmaf(a0.y, bbv[1], a0.x * bbv[0]);
        sA = fmaf(a0.z, bbv[2], sA); sA = fmaf(a0.w, bbv[3], sA);
        float sB = fmaf(a1.y, bbv[5], a1.x * bbv[4]);
        sB = fmaf(a1.z, bbv[6], sB); sB = fmaf(a1.w, bbv[7], sB);
        float s = row8_sum(sA + sB);
        float btv = Xp[t * 32 + col] - s;
        if (rr == (t & 7)) {
          bbv[t >> 3] = btv;
          int Lb = (col << 7) + (t << 1);
          int Pb = Lb ^ ((col & 7) << 4);
          *(unsigned short*)(smem + OFF_BT + Pb)  = f2bf(btv);
          *(unsigned short*)(smem + OFF_BT2 + Pb) = f2bf(btv * ectp[t]);
        }
      }
    }
    __syncthreads();

    // ---- T5: O = oq + M@B (global write); S = ecC*S + B2^T@K (via kT); St writes ----
    {
      f32x4 accO[2];
#pragma unroll
      for (int nt = 0; nt < 2; ++nt)
        accO[nt] = (f32x4){oq[nt * 4 + 0], oq[nt * 4 + 1], oq[nt * 4 + 2], oq[nt * 4 + 3]};
#pragma unroll
      for (int kk2 = 0; kk2 < 2; ++kk2) {
        int ke = kk2 * 32 + lq * 8;
        short8 aM = ldswz7(smem + OFF_MM, 16 * wid + lr, ke);
#pragma unroll
        for (int nt = 0; nt < 2; ++nt) {
          short8 bB = ldswz7(smem + OFF_BT, 16 * nt + lr, ke);
          accO[nt] = __builtin_amdgcn_mfma_f32_16x16x32_bf16(aM, bB, accO[nt], 0, 0, 0);
        }
      }
#pragma unroll
      for (int nt = 0; nt < 2; ++nt)
#pragma unroll
        for (int j = 0; j < 4; ++j) {
          int t = 16 * wid + lq * 4 + j;
          int vcl = nt * 16 + lr;
          long tg = (long)(bat * TT + ct * CC + t);
          ob[(tg * 32 + h) * 128 + vc * 32 + vcl] = f2bf(accO[nt][j]);
        }

      int mr = wid & 1, nc0 = (wid >> 1) * 4;
      f32x4 accP[4] = {};
#pragma unroll
      for (int kk2 = 0; kk2 < 2; ++kk2) {
        int ke = kk2 * 32 + lq * 8;
        short8 aB2 = ldswz7(smem + OFF_BT2, 16 * mr + lr, ke);
#pragma unroll
        for (int c4 = 0; c4 < 4; ++c4) {
          short8 bK = ldswz7(smem + OFF_KT, 16 * (nc0 + c4) + lr, ke);
          accP[c4] = __builtin_amdgcn_mfma_f32_16x16x32_bf16(aB2, bK, accP[c4], 0, 0, 0);
        }
      }
      float ecC = ((const float*)(smem + OFF_EXC))[63];
#pragma unroll
      for (int c4 = 0; c4 < 4; ++c4)
#pragma unroll
        for (int j = 0; j < 4; ++j) {
          float sv = fmaf(ecC, Smast[c4][j], accP[c4][j]);
          Smast[c4][j] = sv;
          int vcr = 16 * mr + lq * 4 + j;
          int dk  = 16 * (nc0 + c4) + lr;
          int Ls = (vcr << 8) + (dk << 1);
          int Ps = Ls ^ ((vcr & 7) << 4);
          unsigned short hi = f2bf(sv);
          *(unsigned short*)(smem + OFF_SH + Ps) = hi;
          *(unsigned short*)(smem + OFF_SL + Ps) = f2bf(sv - bf2f(hi));
        }
    }
    asm volatile("s_waitcnt vmcnt(0)" ::: "memory");
    __syncthreads();
  }
}

// ---------------- gated RMSNorm * silu(z) -> bf16 ----------------
__global__ __launch_bounds__(256) void norm_silu(const unsigned short* __restrict__ ob,
                                                 const unsigned short* __restrict__ C1,
                                                 const float* __restrict__ nw,
                                                 unsigned short* __restrict__ nrm) {
  int unit = blockIdx.x * 4 + (threadIdx.x >> 6);   // m*32+h
  int lane = threadIdx.x & 63;
  int m = unit >> 5, h = unit & 31;
  unsigned int uo = *(const unsigned int*)&ob[(long)unit * 128 + lane * 2];
  float o0 = bf2f((unsigned short)(uo & 0xffff));
  float o1 = bf2f((unsigned short)(uo >> 16));
  float ss = o0 * o0 + o1 * o1;
#pragma unroll
  for (int mm = 1; mm < 64; mm <<= 1) ss += __shfl_xor(ss, mm);
  float rs = rsqrtf(ss * (1.0f / 128.0f) + 1e-6f);
  unsigned int uz = *(const unsigned int*)&C1[(long)m * N1PAD + 8192 + h * 128 + lane * 2];
  float z0 = bf2f((unsigned short)(uz & 0xffff));
  float z1 = bf2f((unsigned short)(uz >> 16));
  float s0 = z0 / (1.f + expf(-z0));
  float s1 = z1 / (1.f + expf(-z1));
  float r0 = o0 * rs * nw[lane * 2] * s0;
  float r1 = o1 * rs * nw[lane * 2 + 1] * s1;
  unsigned int pk = (unsigned int)f2bf(r0) | ((unsigned int)f2bf(r1) << 16);
  *(unsigned int*)&nrm[(long)unit * 128 + lane * 2] = pk;
}

extern "C" void kernel_launch(void* const* d_in, const int* in_sizes, int n_in,
                              void* d_out, int out_size, void* d_ws, size_t ws_size,
                              hipStream_t stream) {
  const float* x    = (const float*)d_in[0];
  const float* Wqkv = (const float*)d_in[2];
  const float* Wz   = (const float*)d_in[3];
  const float* Wb   = (const float*)d_in[4];
  const float* Wa   = (const float*)d_in[5];
  const float* convw= (const float*)d_in[6];
  const float* dtb  = (const float*)d_in[7];
  const float* Alog = (const float*)d_in[8];
  const float* nw   = (const float*)d_in[9];
  const float* Wout = (const float*)d_in[10];
  float* out = (float*)d_out;

  char* ws = (char*)d_ws;
  const size_t OFF_C1    = 0;                    // bf16 [4096][12416]
  const size_t OFF_XB    = 101711872;            // bf16 [4096][2048]
  const size_t OFF_WCAT  = 118489088;            // bf16 [12416][2048]
  const size_t OFF_QB    = OFF_XB;               // over xb (post-GEMM1)
  const size_t OFF_KB    = 118489088;            // over wcat
  const size_t OFF_VB    = 135266304;            // over wcat
  const size_t OFF_EG    = 169345024;            // f32  [4096][32]  (raw g)
  const size_t OFF_BE    = 169869312;
  const size_t OFF_OB    = 170393600;            // bf16 [4096][32][128]
  const size_t OFF_NRM   = OFF_QB;               // over qb+kb (post-scan)
  const size_t OFF_WOUTB = OFF_VB;               // over vb (post-scan)

  unsigned short* C1    = (unsigned short*)(ws + OFF_C1);
  unsigned short* xb    = (unsigned short*)(ws + OFF_XB);
  unsigned short* wcat  = (unsigned short*)(ws + OFF_WCAT);
  unsigned short* qbuf  = (unsigned short*)(ws + OFF_QB);
  unsigned short* kbuf  = (unsigned short*)(ws + OFF_KB);
  unsigned short* vbuf  = (unsigned short*)(ws + OFF_VB);
  float*          egb   = (float*)(ws + OFF_EG);
  float*          betab = (float*)(ws + OFF_BE);
  unsigned short* obuf  = (unsigned short*)(ws + OFF_OB);
  unsigned short* nrm   = (unsigned short*)(ws + OFF_NRM);
  unsigned short* woutb = (unsigned short*)(ws + OFF_WOUTB);
  (void)ws_size; (void)in_sizes; (void)n_in; (void)out_size;

  static int smem_set = 0;
  if (!smem_set) {
    hipFuncSetAttribute(reinterpret_cast<const void*>(chunk_scan),
                        hipFuncAttributeMaxDynamicSharedMemorySize, SMEM_SZ);
    smem_set = 1;
  }

  cvt_bf16<<<8192, 256, 0, stream>>>(x, xb);
  build_wcat<<<24832, 256, 0, stream>>>(Wqkv, Wz, Wb, Wa, wcat);
  gemm_bt<true><<<dim3(N1PAD / 128, M_ROWS / 128), 256, 0, stream>>>(xb, wcat, C1, N1PAD, 2048);
  conv_silu<<<512, 256, 0, stream>>>(C1, convw, qbuf, kbuf, vbuf);
  gbeta<<<512, 256, 0, stream>>>(C1, Alog, dtb, egb, betab);
  l2norm<<<16384, 256, 0, stream>>>(qbuf, 0.08838834764831845f);   // fold DK^-0.5 into q
  l2norm<<<16384, 256, 0, stream>>>(kbuf, 1.0f);
  chunk_scan<<<256, 256, SMEM_SZ, stream>>>(qbuf, kbuf, vbuf, egb, betab, obuf);
  cvt_bf16<<<8192, 256, 0, stream>>>(Wout, woutb);
  norm_silu<<<32768, 256, 0, stream>>>(obuf, C1, nw, nrm);
  gemm_bt<false><<<dim3(2048 / 128, M_ROWS / 128), 256, 0, stream>>>(nrm, woutb, out, 2048, 4096);
}